// Round 8
// baseline (194.211 us; speedup 1.0000x reference)
//
#include <hip/hip_runtime.h>

typedef __bf16 bf16;
typedef __bf16 bf16x4 __attribute__((ext_vector_type(4)));
typedef __bf16 bf16x8 __attribute__((ext_vector_type(8)));
typedef short s16x4 __attribute__((ext_vector_type(4)));
typedef float f32x4 __attribute__((ext_vector_type(4)));

constexpr int BATCH = 2;
constexpr int SEQ   = 2048;
constexpr int DMODEL= 1024;
constexpr int NH    = 16;
constexpr int HD    = 64;
constexpr int M_ROWS= BATCH * SEQ;      // 4096
constexpr int N_QKV = 3 * DMODEL;       // 3072

#if defined(__HIP_DEVICE_COMPILE__) && __has_builtin(__builtin_amdgcn_exp2f)
#define EXP2(x) __builtin_amdgcn_exp2f(x)
#else
#define EXP2(x) exp2f(x)
#endif

// async global->LDS, 16B per lane; LDS dest is wave-uniform base + lane*16
__device__ __forceinline__ void gl_lds16(const bf16* g, bf16* l) {
  __builtin_amdgcn_global_load_lds(
      (const __attribute__((address_space(1))) unsigned int*)g,
      (__attribute__((address_space(3))) unsigned int*)l, 16, 0, 0);
}

// K=16 bf16 MFMA (v_mfma_f32_16x16x16_bf16, short4 operands)
__device__ __forceinline__ f32x4 mfma_16x16x16_bf16(bf16x4 a, bf16x4 b,
                                                    f32x4 c) {
#if defined(__HIP_DEVICE_COMPILE__)
  union { bf16x4 h; s16x4 s; } ua{a}, ub{b};
  return __builtin_amdgcn_mfma_f32_16x16x16bf16_1k(ua.s, ub.s, c, 0, 0, 0);
#else
  return c;  // host pass only needs this to parse
#endif
}

// ---------------------------------------------------------------------------
// Fused prep: cast x -> bf16 (blocks 0..2047), transpose+cast w_qkv
// (2048..5119), transpose+cast w_out (5120..6143).  Transpose vectorized.
// ---------------------------------------------------------------------------
__global__ __launch_bounds__(256) void prep_kernel(
    const float* __restrict__ x, const float* __restrict__ w_qkv,
    const float* __restrict__ w_out, bf16* __restrict__ xb,
    bf16* __restrict__ WqkvT, bf16* __restrict__ WoutT) {
  const int bx = blockIdx.x, t = threadIdx.x;
  if (bx < 2048) {  // cast region
    const int i = (bx * 256 + t) * 8;
    float4 f0 = *(const float4*)&x[i];
    float4 f1 = *(const float4*)&x[i + 4];
    bf16x8 v;
    v[0] = (bf16)f0.x; v[1] = (bf16)f0.y; v[2] = (bf16)f0.z; v[3] = (bf16)f0.w;
    v[4] = (bf16)f1.x; v[5] = (bf16)f1.y; v[6] = (bf16)f1.z; v[7] = (bf16)f1.w;
    *(bf16x8*)&xb[i] = v;
    return;
  }
  __shared__ float tile[32][33];
  const float* src;
  bf16* dst;
  int R, C, c0, r0;
  if (bx < 5120) {
    const int idx = bx - 2048;           // 96 x 32 tiles
    src = w_qkv; dst = WqkvT; R = DMODEL; C = N_QKV;
    c0 = (idx % 96) * 32; r0 = (idx / 96) * 32;
  } else {
    const int idx = bx - 5120;           // 32 x 32 tiles
    src = w_out; dst = WoutT; R = DMODEL; C = DMODEL;
    c0 = (idx & 31) * 32; r0 = (idx >> 5) * 32;
  }
  const int r = t >> 3, c4 = (t & 7) * 4;
  {
    float4 f = *(const float4*)&src[(size_t)(r0 + r) * C + c0 + c4];
    tile[r][c4 + 0] = f.x; tile[r][c4 + 1] = f.y;
    tile[r][c4 + 2] = f.z; tile[r][c4 + 3] = f.w;
  }
  __syncthreads();
  {
    bf16x4 v;
#pragma unroll
    for (int j = 0; j < 4; j++) v[j] = (bf16)tile[c4 + j][r];
    *(bf16x4*)&dst[(size_t)(c0 + r) * R + r0 + c4] = v;
  }
}

// ---------------------------------------------------------------------------
// Out-projection GEMM, 64x128 tile, NOW double-buffered prefetch-early:
// stage tile k+1 at the TOP of iter k, compute, barrier (its vmcnt(0) drain
// hits loads that had the whole MFMA phase to land).  1 barrier/iter.
// ---------------------------------------------------------------------------
__global__ __launch_bounds__(256) void gemm_out64(
    const bf16* __restrict__ A, const bf16* __restrict__ BT,
    float* __restrict__ C, int M, int N, int K) {
  __shared__ bf16 As[2][2048];
  __shared__ bf16 Bs[2][4096];
  const int t = threadIdx.x;
  const int m0 = blockIdx.y * 64;
  const int n0 = blockIdx.x * 128;
  const int w = t >> 6, lane = t & 63, g = lane >> 4, li = lane & 15;
  const int r0w = (w & 1) * 32, c0w = (w >> 1) * 64;
  f32x4 acc[2][4] = {};
  const int ia = w * 64 + lane;
  const int ra = ia >> 2, ca = (ia & 3) * 8;
  const int ib0 = (w * 2 + 0) * 64 + lane, ib1 = (w * 2 + 1) * 64 + lane;
  const int rb0 = ib0 >> 2, cb0 = (ib0 & 3) * 8;
  const int rb1 = ib1 >> 2, cb1 = (ib1 & 3) * 8;

#define OUT_STAGE(buf, k0)                                                   \
  {                                                                          \
    gl_lds16(&A[(size_t)(m0 + ra) * K + (k0) + ca], &As[buf][w * 512]);      \
    gl_lds16(&BT[(size_t)(n0 + rb0) * K + (k0) + cb0],                       \
             &Bs[buf][(w * 2 + 0) * 512]);                                   \
    gl_lds16(&BT[(size_t)(n0 + rb1) * K + (k0) + cb1],                       \
             &Bs[buf][(w * 2 + 1) * 512]);                                   \
  }

  OUT_STAGE(0, 0);
  __syncthreads();   // includes vmcnt(0) drain
  for (int it = 0; it < 32; ++it) {
    const int cur = it & 1;
    if (it < 31) OUT_STAGE(cur ^ 1, (it + 1) * 32);
    bf16x8 a[2], b[4];
#pragma unroll
    for (int mt = 0; mt < 2; mt++)
      a[mt] = *(const bf16x8*)&As[cur][(r0w + mt * 16 + li) * 32 + g * 8];
#pragma unroll
    for (int nt = 0; nt < 4; nt++)
      b[nt] = *(const bf16x8*)&Bs[cur][(c0w + nt * 16 + li) * 32 + g * 8];
#pragma unroll
    for (int mt = 0; mt < 2; mt++)
#pragma unroll
      for (int nt = 0; nt < 4; nt++)
        acc[mt][nt] = __builtin_amdgcn_mfma_f32_16x16x32_bf16(
            a[mt], b[nt], acc[mt][nt], 0, 0, 0);
    __syncthreads();  // drains the prefetch issued above (cheap by now)
  }
#undef OUT_STAGE

#pragma unroll
  for (int mt = 0; mt < 2; mt++)
#pragma unroll
    for (int nt = 0; nt < 4; nt++)
#pragma unroll
      for (int r = 0; r < 4; r++) {
        const int m = m0 + r0w + mt * 16 + g * 4 + r;
        const int n = n0 + c0w + nt * 16 + li;
        C[(size_t)m * N + n] = acc[mt][nt][r];
      }
}

// ---------------------------------------------------------------------------
// QKV GEMM + fused RoPE, double-buffered prefetch-early (same transform).
// LDS 32KB: [As0|As1|Bs0|Bs1] 4x4096 bf16; epilogue reuses smem[0..8448).
// Q pre-scaled by 1/sqrt(hd)*log2(e).
// ---------------------------------------------------------------------------
__global__ __launch_bounds__(256) void gemm_qkv_rope(
    const bf16* __restrict__ A, const bf16* __restrict__ BT,
    bf16* __restrict__ Qb, bf16* __restrict__ Kb, bf16* __restrict__ Vt) {
  constexpr int K = DMODEL;
  __shared__ bf16 smem[16384];
  const int t = threadIdx.x;
  const int m0 = blockIdx.y * 128;
  const int n0 = blockIdx.x * 128;
  const int w = t >> 6, lane = t & 63, g = lane >> 4, li = lane & 15;
  const int r0w = (w & 1) * 64, c0w = (w >> 1) * 64;
  f32x4 acc[4][4] = {};

  const int i0 = (w * 2 + 0) * 64 + lane, i1 = (w * 2 + 1) * 64 + lane;
  const int sr0 = i0 >> 2, sc0 = (i0 & 3) * 8;
  const int sr1 = i1 >> 2, sc1 = (i1 & 3) * 8;

#define QKV_STAGE(buf, k0)                                                   \
  {                                                                          \
    bf16* Asb = smem + (buf)*4096;                                           \
    bf16* Bsb = smem + 8192 + (buf)*4096;                                    \
    gl_lds16(&A[(size_t)(m0 + sr0) * K + (k0) + sc0],                        \
             &Asb[(w * 2 + 0) * 512]);                                       \
    gl_lds16(&A[(size_t)(m0 + sr1) * K + (k0) + sc1],                        \
             &Asb[(w * 2 + 1) * 512]);                                       \
    gl_lds16(&BT[(size_t)(n0 + sr0) * K + (k0) + sc0],                       \
             &Bsb[(w * 2 + 0) * 512]);                                       \
    gl_lds16(&BT[(size_t)(n0 + sr1) * K + (k0) + sc1],                       \
             &Bsb[(w * 2 + 1) * 512]);                                       \
  }

  QKV_STAGE(0, 0);
  __syncthreads();   // includes vmcnt(0) drain
  for (int it = 0; it < 32; ++it) {
    const int cur = it & 1;
    if (it < 31) QKV_STAGE(cur ^ 1, (it + 1) * 32);
    const bf16* Asb = smem + cur * 4096;
    const bf16* Bsb = smem + 8192 + cur * 4096;
    bf16x8 a[4], b[4];
#pragma unroll
    for (int mt = 0; mt < 4; mt++)
      a[mt] = *(const bf16x8*)&Asb[(r0w + mt * 16 + li) * 32 + g * 8];
#pragma unroll
    for (int nt = 0; nt < 4; nt++)
      b[nt] = *(const bf16x8*)&Bsb[(c0w + nt * 16 + li) * 32 + g * 8];
#pragma unroll
    for (int mt = 0; mt < 4; mt++)
#pragma unroll
      for (int nt = 0; nt < 4; nt++)
        acc[mt][nt] = __builtin_amdgcn_mfma_f32_16x16x32_bf16(
            a[mt], b[nt], acc[mt][nt], 0, 0, 0);
    __syncthreads();  // drains the prefetch issued above (cheap by now)
  }
#undef QKV_STAGE

  const int region = n0 >> 10;               // 0=q, 1=k, 2=v
  const int b = m0 >> 11;                    // batch (block-uniform)
  const int h = ((n0 + c0w) >> 6) & 15;      // head (wave-uniform)
  const size_t bh = (size_t)(b * NH + h);

  if (region < 2) {
    bf16* dst = region == 0 ? Qb : Kb;
    const float outsc = region == 0 ? 0.125f * 1.44269504f : 1.f;
    const float L = 13.287712379549449f;  // log2(10000)
    const float if0 = exp2f(-(float)(2 * li) / 64.f * L);
    const float if1 = exp2f(-(float)(2 * (li + 16)) / 64.f * L);
    bf16* lw = smem + w * 2112;           // 32 rows x stride 66
#pragma unroll
    for (int pass = 0; pass < 2; pass++) {
      __syncthreads();  // fence GEMM-LDS / previous-pass reads
#pragma unroll
      for (int mtl = 0; mtl < 2; mtl++) {
        const int mt = pass * 2 + mtl;
#pragma unroll
        for (int r = 0; r < 4; r++) {
          const int s = (m0 + r0w + mt * 16 + g * 4 + r) & (SEQ - 1);
          float cs[2], sn[2];
          __sincosf((float)s * if0, &sn[0], &cs[0]);
          __sincosf((float)s * if1, &sn[1], &cs[1]);
#pragma unroll
          for (int nt = 0; nt < 4; nt++) {
            const int par = nt & 1;
            const float a = acc[mt][nt][r];
            const float ap = acc[mt][nt ^ 2][r];
            const float v = (nt < 2) ? a * cs[par] - ap * sn[par]
                                     : a * cs[par] + ap * sn[par];
            lw[(mtl * 16 + g * 4 + r) * 66 + nt * 16 + li] =
                (bf16)(v * outsc);
          }
        }
      }
      __syncthreads();
      // coalesced store: lane L -> row L>>1, d-half (L&1)*32
      const int rowl = lane >> 1, dh = (lane & 1) * 32;
      const int s = (m0 + r0w + pass * 32 + rowl) & (SEQ - 1);
      bf16* gdst = &dst[(bh * SEQ + s) * HD + dh];
      const bf16* lsrc = &lw[rowl * 66 + dh];
#pragma unroll
      for (int c = 0; c < 4; c++)
        *(bf16x8*)&gdst[c * 8] = *(const bf16x8*)&lsrc[c * 8];
    }
  } else {
    // V: transpose-scatter, pack 4 consecutive s per store
#pragma unroll
    for (int mt = 0; mt < 4; mt++)
#pragma unroll
      for (int nt = 0; nt < 4; nt++) {
        const int s = (m0 + r0w + mt * 16 + g * 4) & (SEQ - 1);
        const int d = nt * 16 + li;
        bf16x4 v;
#pragma unroll
        for (int r = 0; r < 4; r++) v[r] = (bf16)acc[mt][nt][r];
        *(bf16x4*)&Vt[(bh * HD + d) * SEQ + s] = v;
      }
  }
}

// ---------------------------------------------------------------------------
// Flash attention v15 (unchanged from R7): full <=8-iter chunking, packed
// deterministic partials, 5 blocks/CU, hoisted LDS offsets, clean/masked
// loop split, native exp2.
// entry byte = qt*4 + chunk.
// ---------------------------------------------------------------------------
__device__ const unsigned char CHUNK_TAB[80] = {
    124, 125, 126, 127,
    120, 121, 122, 116, 117, 118, 112, 113, 114, 108, 109, 110,
    104, 105, 106, 100, 101, 102, 96,  97,  98,  92,  93,  94,
    88,  89,  84,  85,  80,  81,  76,  77,  72,  73,  68,  69,
    64,  65,  60,  61,
    56,  52,  48,  44,  40,  36,  32,  28,
    24,  57,  90,  123, 20,  53,  86,  119, 16,  49,  82,  115,
    12,  45,  78,  111, 8,   41,  74,  107, 4,   37,  70,  103,
    0,   33,  66,  99};

__global__ __launch_bounds__(256, 5) void flash_attn15(
    const bf16* __restrict__ Q, const bf16* __restrict__ Kb,
    const bf16* __restrict__ Vt, bf16* __restrict__ Oout,
    float* __restrict__ Opart, float* __restrict__ Lpart) {
  const int bx = blockIdx.x;         // 0..2559
  const unsigned char e = CHUNK_TAB[bx >> 5];
  const int qt = e >> 2, kch = e & 3;
  const int bh = bx & 31;
  const int q0 = qt * 64;
  const int jlo = kch * 8;
  const int jhi = min(jlo + 8, qt + 1);
  const int t = threadIdx.x, w = t >> 6, lane = t & 63, g = lane >> 4,
            li = lane & 15;

  __shared__ bf16 Ks[2][4096];
  __shared__ bf16 Vs[2][4096];

  const bf16* Qh = Q  + (size_t)bh * SEQ * HD;
  const bf16* Kh = Kb + (size_t)bh * SEQ * HD;
  const bf16* Vh = Vt + (size_t)bh * HD * SEQ;

  const int qw = q0 + w * 16;        // this wave's 16 q-rows (q = qw + li)

  bf16x8 qf[2];
#pragma unroll
  for (int ks = 0; ks < 2; ks++)
    qf[ks] = *(const bf16x8*)&Qh[(size_t)(qw + li) * HD + ks * 32 + g * 8];

  f32x4 o[4] = {};   // O^T[dv = dt*16 + g*4 + r][q = li]
  f32x4 o4  = {};    // ones-row accumulator -> l(q=li)
  bf16x4 ones;
#pragma unroll
  for (int r = 0; r < 4; r++) ones[r] = (bf16)1.f;

  // hoisted LDS byte offsets (static-indexed after unroll -> registers)
  int koffB[2][4];
#pragma unroll
  for (int ks = 0; ks < 2; ks++)
#pragma unroll
    for (int nt = 0; nt < 4; nt++) {
      const int rK = nt * 16 + li;
      const int pK = rK * 8 + ((ks * 4 + g) ^ (li & 7));
      koffB[ks][nt] = pK * 16;
    }
  int voffB[4][4];
#pragma unroll
  for (int nt = 0; nt < 4; nt++)
#pragma unroll
    for (int dt = 0; dt < 4; dt++) {
      const int rV = dt * 16 + li;
      const int cg = nt * 2 + (g >> 1);
      const int pV = rV * 8 + (cg ^ (rV & 7));
      voffB[nt][dt] = pV * 16 + (g & 1) * 8;
    }

  const int p0 = w * 128 + lane, p1 = p0 + 64;
  const int sr0 = p0 >> 3, sc0 = ((p0 & 7) ^ (sr0 & 7)) * 8;
  const int sr1 = p1 >> 3, sc1 = ((p1 & 7) ^ (sr1 & 7)) * 8;
  const int lo0 = w * 1024, lo1 = w * 1024 + 512;

  {
    const int jn = jlo * 64;
    gl_lds16(&Kh[(size_t)(jn + sr0) * HD + sc0], &Ks[jlo & 1][lo0]);
    gl_lds16(&Kh[(size_t)(jn + sr1) * HD + sc1], &Ks[jlo & 1][lo1]);
    gl_lds16(&Vh[(size_t)sr0 * SEQ + jn + sc0], &Vs[jlo & 1][lo0]);
    gl_lds16(&Vh[(size_t)sr1 * SEQ + jn + sc1], &Vs[jlo & 1][lo1]);
  }
  __syncthreads();

  for (int ti = jlo; ti < jhi; ++ti) {
    const int cur = ti & 1, nxt = cur ^ 1;
    const char* ksb = (const char*)&Ks[cur][0];
    const char* vsb = (const char*)&Vs[cur][0];
    if (ti + 1 < jhi) {
      const int jn = ti * 64 + 64;
      gl_lds16(&Kh[(size_t)(jn + sr0) * HD + sc0], &Ks[nxt][lo0]);
      gl_lds16(&Kh[(size_t)(jn + sr1) * HD + sc1], &Ks[nxt][lo1]);
      gl_lds16(&Vh[(size_t)sr0 * SEQ + jn + sc0], &Vs[nxt][lo0]);
      gl_lds16(&Vh[(size_t)sr1 * SEQ + jn + sc1], &Vs[nxt][lo1]);
    }

    if (ti < qt) {
      // clean tile: no masking, all 4 nt fragments
      f32x4 sacc[4] = {};
      __builtin_amdgcn_s_setprio(1);
#pragma unroll
      for (int ks = 0; ks < 2; ks++)
#pragma unroll
        for (int nt = 0; nt < 4; nt++) {
          bf16x8 kf = *(const bf16x8*)(ksb + koffB[ks][nt]);
          sacc[nt] = __builtin_amdgcn_mfma_f32_16x16x32_bf16(kf, qf[ks],
                                                             sacc[nt], 0, 0, 0);
        }
      __builtin_amdgcn_s_setprio(0);

      bf16x4 pf[4];
#pragma unroll
      for (int nt = 0; nt < 4; nt++)
#pragma unroll
        for (int r = 0; r < 4; r++) pf[nt][r] = (bf16)EXP2(sacc[nt][r]);

      __builtin_amdgcn_s_setprio(1);
#pragma unroll
      for (int nt = 0; nt < 4; nt++) {
        o4 = mfma_16x16x16_bf16(ones, pf[nt], o4);
#pragma unroll
        for (int dt = 0; dt < 4; dt++) {
          bf16x4 vfrag = *(const bf16x4*)(vsb + voffB[nt][dt]);
          o[dt] = mfma_16x16x16_bf16(vfrag, pf[nt], o[dt]);
        }
      }
      __builtin_amdgcn_s_setprio(0);
    } else {
      // diagonal tile (ti == qt): fragments nt<w clean, nt==w masked,
      // nt>w entirely below the causal boundary
      f32x4 sacc[4] = {};
      __builtin_amdgcn_s_setprio(1);
#pragma unroll
      for (int ks = 0; ks < 2; ks++)
#pragma unroll
        for (int nt = 0; nt < 4; nt++) {
          if (nt > w) continue;
          bf16x8 kf = *(const bf16x8*)(ksb + koffB[ks][nt]);
          sacc[nt] = __builtin_amdgcn_mfma_f32_16x16x32_bf16(kf, qf[ks],
                                                             sacc[nt], 0, 0, 0);
        }
      __builtin_amdgcn_s_setprio(0);

      bf16x4 pf[4];
#pragma unroll
      for (int nt = 0; nt < 4; nt++) {
        if (nt > w) continue;
#pragma unroll
        for (int r = 0; r < 4; r++) {
          float v = sacc[nt][r];
          if (nt == w) {
            const int kk = nt * 16 + g * 4 + r;
            v = (kk <= w * 16 + li) ? v : -1e30f;
          }
          pf[nt][r] = (bf16)EXP2(v);
        }
      }

      __builtin_amdgcn_s_setprio(1);
#pragma unroll
      for (int nt = 0; nt < 4; nt++) {
        if (nt > w) continue;
        o4 = mfma_16x16x16_bf16(ones, pf[nt], o4);
#pragma unroll
        for (int dt = 0; dt < 4; dt++) {
          bf16x4 vfrag = *(const bf16x4*)(vsb + voffB[nt][dt]);
          o[dt] = mfma_16x16x16_bf16(vfrag, pf[nt], o[dt]);
        }
      }
      __builtin_amdgcn_s_setprio(0);
    }
    __syncthreads();
  }

  if (qt <= 7) {
    // single chunk: direct normalized store (rows s < 512)
    const float inv_l = 1.f / o4[0];
    const int b = bh >> 4, h = bh & 15;
    const int s = qw + li;
#pragma unroll
    for (int dt = 0; dt < 4; dt++) {
      bf16x4 ov;
#pragma unroll
      for (int r = 0; r < 4; r++) ov[r] = (bf16)(o[dt][r] * inv_l);
      *(bf16x4*)&Oout[((size_t)(b * SEQ + s)) * DMODEL + h * 64 + dt * 16 +
                      g * 4] = ov;
    }
  } else {
    // packed deterministic partial slot: 2/3/4 slots per row by qt band
    const int s = qw + li;
    int off;
    if (qt < 16)       off = (s - 512) * 2 + kch;
    else if (qt < 24)  off = 1024 + (s - 1024) * 3 + kch;
    else               off = 2560 + (s - 1536) * 4 + kch;
    const size_t slot = (size_t)bh * 4608 + off;
    if (g == 0) Lpart[slot] = o4[0];
    float* od = &Opart[slot * 64];
#pragma unroll
    for (int dt = 0; dt < 4; dt++)
      *(f32x4*)&od[dt * 16 + g * 4] = o[dt];
  }
}

// ---------------------------------------------------------------------------
// Merge rows s in [512,2048): attn = sum_c(Oc) / sum_c(lc), nc = 2/3/4
// grid 1536 x 256, 8 floats/thread
// ---------------------------------------------------------------------------
__global__ __launch_bounds__(256) void attn_merge2(
    const float* __restrict__ Opart, const float* __restrict__ Lpart,
    bf16* __restrict__ attn) {
  const int gi = blockIdx.x * 256 + threadIdx.x;  // 0..393215
  const int row = gi >> 3;                        // bh*1536 + srel
  const int d0 = (gi & 7) * 8;
  const int bh = row / 1536, srel = row - bh * 1536;
  const int b = bh >> 4, h = bh & 15, s = srel + 512;
  int off0, nc;
  if (srel < 512)       { off0 = srel * 2;                nc = 2; }
  else if (srel < 1024) { off0 = 1024 + (srel - 512) * 3; nc = 3; }
  else                  { off0 = 2560 + (srel - 1024) * 4; nc = 4; }
  const size_t base = (size_t)bh * 4608 + off0;
  float lsum = 0.f;
  float acc[8] = {};
  for (int c = 0; c < nc; c++) {
    lsum += Lpart[base + c];
    const float* p = &Opart[(base + c) * 64 + d0];
    float4 a0 = *(const float4*)p;
    float4 a1 = *(const float4*)(p + 4);
    acc[0] += a0.x; acc[1] += a0.y; acc[2] += a0.z; acc[3] += a0.w;
    acc[4] += a1.x; acc[5] += a1.y; acc[6] += a1.z; acc[7] += a1.w;
  }
  const float inv = 1.f / lsum;
  bf16x8 v;
#pragma unroll
  for (int i = 0; i < 8; i++) v[i] = (bf16)(acc[i] * inv);
  *(bf16x8*)&attn[((size_t)(b * SEQ + s)) * DMODEL + h * 64 + d0] = v;
}

// ---------------------------------------------------------------------------
// Launch
// ---------------------------------------------------------------------------
extern "C" void kernel_launch(void* const* d_in, const int* in_sizes, int n_in,
                              void* d_out, int out_size, void* d_ws,
                              size_t ws_size, hipStream_t stream) {
  const float* x     = (const float*)d_in[0];
  // d_in[1] = causal mask (int32) — causality implemented directly
  const float* w_qkv = (const float*)d_in[2];
  const float* w_out = (const float*)d_in[3];
  float* out = (float*)d_out;

  char* ws = (char*)d_ws;
  bf16* WqkvT = (bf16*)(ws);                        //  6,291,456 B
  bf16* WoutT = (bf16*)(ws + 6291456);              //  2,097,152 B
  bf16* xb    = (bf16*)(ws + 8388608);              //  8,388,608 B
  bf16* Qb    = (bf16*)(ws + 16777216);             //  8,388,608 B
  bf16* Kbuf  = (bf16*)(ws + 25165824);             //  8,388,608 B
  bf16* Vt    = (bf16*)(ws + 33554432);             //  8,388,608 B
  bf16* attn  = (bf16*)(ws + 41943040);             //  8,388,608 B
  float* Opart= (float*)(ws + 50331648);            // 37,748,736 B
  float* Lpart= (float*)(ws + 88080384);            //    589,824 B (end ~88.7MB)

  prep_kernel<<<dim3(6144), 256, 0, stream>>>(x, w_qkv, w_out, xb, WqkvT,
                                              WoutT);
  gemm_qkv_rope<<<dim3(N_QKV / 128, M_ROWS / 128), 256, 0, stream>>>(
      xb, WqkvT, Qb, Kbuf, Vt);
  flash_attn15<<<dim3(2560), 256, 0, stream>>>(Qb, Kbuf, Vt, attn, Opart,
                                               Lpart);
  attn_merge2<<<dim3(1536), 256, 0, stream>>>(Opart, Lpart, attn);
  gemm_out64<<<dim3(DMODEL / 128, M_ROWS / 64), 256, 0, stream>>>(
      attn, WoutT, out, M_ROWS, DMODEL, DMODEL);
}

// Round 9
// 190.026 us; speedup vs baseline: 1.0220x; 1.0220x over previous
//
#include <hip/hip_runtime.h>

typedef __bf16 bf16;
typedef __bf16 bf16x4 __attribute__((ext_vector_type(4)));
typedef __bf16 bf16x8 __attribute__((ext_vector_type(8)));
typedef short s16x4 __attribute__((ext_vector_type(4)));
typedef float f32x4 __attribute__((ext_vector_type(4)));

constexpr int BATCH = 2;
constexpr int SEQ   = 2048;
constexpr int DMODEL= 1024;
constexpr int NH    = 16;
constexpr int HD    = 64;
constexpr int M_ROWS= BATCH * SEQ;      // 4096
constexpr int N_QKV = 3 * DMODEL;       // 3072

#if defined(__HIP_DEVICE_COMPILE__) && __has_builtin(__builtin_amdgcn_exp2f)
#define EXP2(x) __builtin_amdgcn_exp2f(x)
#else
#define EXP2(x) exp2f(x)
#endif

// async global->LDS, 16B per lane; LDS dest is wave-uniform base + lane*16
__device__ __forceinline__ void gl_lds16(const bf16* g, bf16* l) {
  __builtin_amdgcn_global_load_lds(
      (const __attribute__((address_space(1))) unsigned int*)g,
      (__attribute__((address_space(3))) unsigned int*)l, 16, 0, 0);
}

// K=16 bf16 MFMA (v_mfma_f32_16x16x16_bf16, short4 operands)
__device__ __forceinline__ f32x4 mfma_16x16x16_bf16(bf16x4 a, bf16x4 b,
                                                    f32x4 c) {
#if defined(__HIP_DEVICE_COMPILE__)
  union { bf16x4 h; s16x4 s; } ua{a}, ub{b};
  return __builtin_amdgcn_mfma_f32_16x16x16bf16_1k(ua.s, ub.s, c, 0, 0, 0);
#else
  return c;  // host pass only needs this to parse
#endif
}

// ---------------------------------------------------------------------------
// Fused prep: cast x -> bf16 (blocks 0..2047), transpose+cast w_qkv
// (2048..5119), transpose+cast w_out (5120..6143).  Transpose vectorized.
// ---------------------------------------------------------------------------
__global__ __launch_bounds__(256) void prep_kernel(
    const float* __restrict__ x, const float* __restrict__ w_qkv,
    const float* __restrict__ w_out, bf16* __restrict__ xb,
    bf16* __restrict__ WqkvT, bf16* __restrict__ WoutT) {
  const int bx = blockIdx.x, t = threadIdx.x;
  if (bx < 2048) {  // cast region
    const int i = (bx * 256 + t) * 8;
    float4 f0 = *(const float4*)&x[i];
    float4 f1 = *(const float4*)&x[i + 4];
    bf16x8 v;
    v[0] = (bf16)f0.x; v[1] = (bf16)f0.y; v[2] = (bf16)f0.z; v[3] = (bf16)f0.w;
    v[4] = (bf16)f1.x; v[5] = (bf16)f1.y; v[6] = (bf16)f1.z; v[7] = (bf16)f1.w;
    *(bf16x8*)&xb[i] = v;
    return;
  }
  __shared__ float tile[32][33];
  const float* src;
  bf16* dst;
  int R, C, c0, r0;
  if (bx < 5120) {
    const int idx = bx - 2048;           // 96 x 32 tiles
    src = w_qkv; dst = WqkvT; R = DMODEL; C = N_QKV;
    c0 = (idx % 96) * 32; r0 = (idx / 96) * 32;
  } else {
    const int idx = bx - 5120;           // 32 x 32 tiles
    src = w_out; dst = WoutT; R = DMODEL; C = DMODEL;
    c0 = (idx & 31) * 32; r0 = (idx >> 5) * 32;
  }
  const int r = t >> 3, c4 = (t & 7) * 4;
  {
    float4 f = *(const float4*)&src[(size_t)(r0 + r) * C + c0 + c4];
    tile[r][c4 + 0] = f.x; tile[r][c4 + 1] = f.y;
    tile[r][c4 + 2] = f.z; tile[r][c4 + 3] = f.w;
  }
  __syncthreads();
  {
    bf16x4 v;
#pragma unroll
    for (int j = 0; j < 4; j++) v[j] = (bf16)tile[c4 + j][r];
    *(bf16x4*)&dst[(size_t)(c0 + r) * R + r0 + c4] = v;
  }
}

// ---------------------------------------------------------------------------
// Out-projection GEMM, 64x128 tile (REVERTED to R7 form — the R8 dbuf
// variant coincided with a ~6us rest-of-pipeline regression): C fp32
// ---------------------------------------------------------------------------
__global__ __launch_bounds__(256) void gemm_out64(
    const bf16* __restrict__ A, const bf16* __restrict__ BT,
    float* __restrict__ C, int M, int N, int K) {
  __shared__ bf16 As[64 * 32];
  __shared__ bf16 Bs[128 * 32];
  const int t = threadIdx.x;
  const int m0 = blockIdx.y * 64;
  const int n0 = blockIdx.x * 128;
  const int w = t >> 6, lane = t & 63, g = lane >> 4, li = lane & 15;
  const int r0w = (w & 1) * 32, c0w = (w >> 1) * 64;
  f32x4 acc[2][4] = {};
  for (int k0 = 0; k0 < K; k0 += 32) {
    __syncthreads();
    {
      const int idx = w * 64 + lane;
      const int row = idx >> 2, col = (idx & 3) * 8;
      gl_lds16(&A[(size_t)(m0 + row) * K + k0 + col], &As[w * 512]);
    }
#pragma unroll
    for (int c = 0; c < 2; c++) {
      const int idx = (w * 2 + c) * 64 + lane;
      const int row = idx >> 2, col = (idx & 3) * 8;
      gl_lds16(&BT[(size_t)(n0 + row) * K + k0 + col], &Bs[(w * 2 + c) * 512]);
    }
    __syncthreads();
    bf16x8 a[2], b[4];
#pragma unroll
    for (int mt = 0; mt < 2; mt++)
      a[mt] = *(const bf16x8*)&As[(r0w + mt * 16 + li) * 32 + g * 8];
#pragma unroll
    for (int nt = 0; nt < 4; nt++)
      b[nt] = *(const bf16x8*)&Bs[(c0w + nt * 16 + li) * 32 + g * 8];
#pragma unroll
    for (int mt = 0; mt < 2; mt++)
#pragma unroll
      for (int nt = 0; nt < 4; nt++)
        acc[mt][nt] = __builtin_amdgcn_mfma_f32_16x16x32_bf16(
            a[mt], b[nt], acc[mt][nt], 0, 0, 0);
  }
#pragma unroll
  for (int mt = 0; mt < 2; mt++)
#pragma unroll
    for (int nt = 0; nt < 4; nt++)
#pragma unroll
      for (int r = 0; r < 4; r++) {
        const int m = m0 + r0w + mt * 16 + g * 4 + r;
        const int n = n0 + c0w + nt * 16 + li;
        C[(size_t)m * N + n] = acc[mt][nt][r];
      }
}

// ---------------------------------------------------------------------------
// QKV GEMM + fused RoPE: TRIPLE-buffered, prefetch distance 2, counted
// s_waitcnt vmcnt(4) + raw s_barrier (m201 protocol).  Each wave issues
// exactly 4 gl_lds/tile, so vmcnt arithmetic is deterministic:
//   prologue: stage t0,t1; vmcnt(4) [t0 landed]; barrier
//   iter ti : stage t(i+2); compute buf[ti%3]; vmcnt(4) [t(i+1) landed,
//             t(i+2) stays in flight ACROSS the barrier]; barrier
// LDS 48KB = 3 blocks/CU (grid 768 = 3/CU anyway: zero occupancy cost,
// unlike flash-R1 where this technique lost a residency slot).
// Q pre-scaled by 1/sqrt(hd)*log2(e).
// ---------------------------------------------------------------------------
__global__ __launch_bounds__(256) void gemm_qkv_rope(
    const bf16* __restrict__ A, const bf16* __restrict__ BT,
    bf16* __restrict__ Qb, bf16* __restrict__ Kb, bf16* __restrict__ Vt) {
  constexpr int K = DMODEL;
  __shared__ bf16 smem[24576];  // A bufs @ 0/4096/8192, B bufs @ 12288/16384/20480
  const int t = threadIdx.x;
  const int m0 = blockIdx.y * 128;
  const int n0 = blockIdx.x * 128;
  const int w = t >> 6, lane = t & 63, g = lane >> 4, li = lane & 15;
  const int r0w = (w & 1) * 64, c0w = (w >> 1) * 64;
  f32x4 acc[4][4] = {};

  const int i0 = (w * 2 + 0) * 64 + lane, i1 = (w * 2 + 1) * 64 + lane;
  const int sr0 = i0 >> 2, sc0 = (i0 & 3) * 8;
  const int sr1 = i1 >> 2, sc1 = (i1 & 3) * 8;

#define QKV_STAGE(buf, k0)                                                   \
  {                                                                          \
    bf16* Asb = smem + (buf) * 4096;                                         \
    bf16* Bsb = smem + 12288 + (buf) * 4096;                                 \
    gl_lds16(&A[(size_t)(m0 + sr0) * K + (k0) + sc0],                        \
             &Asb[(w * 2 + 0) * 512]);                                       \
    gl_lds16(&A[(size_t)(m0 + sr1) * K + (k0) + sc1],                        \
             &Asb[(w * 2 + 1) * 512]);                                       \
    gl_lds16(&BT[(size_t)(n0 + sr0) * K + (k0) + sc0],                       \
             &Bsb[(w * 2 + 0) * 512]);                                       \
    gl_lds16(&BT[(size_t)(n0 + sr1) * K + (k0) + sc1],                       \
             &Bsb[(w * 2 + 1) * 512]);                                       \
  }

  QKV_STAGE(0, 0);
  QKV_STAGE(1, 32);
  asm volatile("s_waitcnt vmcnt(4)" ::: "memory");  // tile0 landed
  asm volatile("s_barrier" ::: "memory");

  int cur = 0;
  for (int it = 0; it < 32; ++it) {
    if (it + 2 < 32) QKV_STAGE((it + 2) % 3, (it + 2) * 32);
    const bf16* Asb = smem + cur * 4096;
    const bf16* Bsb = smem + 12288 + cur * 4096;
    bf16x8 a[4], b[4];
#pragma unroll
    for (int mt = 0; mt < 4; mt++)
      a[mt] = *(const bf16x8*)&Asb[(r0w + mt * 16 + li) * 32 + g * 8];
#pragma unroll
    for (int nt = 0; nt < 4; nt++)
      b[nt] = *(const bf16x8*)&Bsb[(c0w + nt * 16 + li) * 32 + g * 8];
#pragma unroll
    for (int mt = 0; mt < 4; mt++)
#pragma unroll
      for (int nt = 0; nt < 4; nt++)
        acc[mt][nt] = __builtin_amdgcn_mfma_f32_16x16x32_bf16(
            a[mt], b[nt], acc[mt][nt], 0, 0, 0);
    // wait only for the tile the NEXT iteration reads; keep the newest
    // 4 loads (prefetch distance 2) in flight across the barrier
    if (it + 2 < 32)
      asm volatile("s_waitcnt vmcnt(4)" ::: "memory");
    else
      asm volatile("s_waitcnt vmcnt(0)" ::: "memory");
    asm volatile("s_barrier" ::: "memory");
    cur = (cur == 2) ? 0 : cur + 1;
  }
#undef QKV_STAGE

  const int region = n0 >> 10;               // 0=q, 1=k, 2=v
  const int b = m0 >> 11;                    // batch (block-uniform)
  const int h = ((n0 + c0w) >> 6) & 15;      // head (wave-uniform)
  const size_t bh = (size_t)(b * NH + h);

  if (region < 2) {
    bf16* dst = region == 0 ? Qb : Kb;
    const float outsc = region == 0 ? 0.125f * 1.44269504f : 1.f;
    const float L = 13.287712379549449f;  // log2(10000)
    const float if0 = exp2f(-(float)(2 * li) / 64.f * L);
    const float if1 = exp2f(-(float)(2 * (li + 16)) / 64.f * L);
    bf16* lw = smem + w * 2112;           // 32 rows x stride 66
#pragma unroll
    for (int pass = 0; pass < 2; pass++) {
      __syncthreads();  // fence GEMM-LDS / previous-pass reads
#pragma unroll
      for (int mtl = 0; mtl < 2; mtl++) {
        const int mt = pass * 2 + mtl;
#pragma unroll
        for (int r = 0; r < 4; r++) {
          const int s = (m0 + r0w + mt * 16 + g * 4 + r) & (SEQ - 1);
          float cs[2], sn[2];
          __sincosf((float)s * if0, &sn[0], &cs[0]);
          __sincosf((float)s * if1, &sn[1], &cs[1]);
#pragma unroll
          for (int nt = 0; nt < 4; nt++) {
            const int par = nt & 1;
            const float a = acc[mt][nt][r];
            const float ap = acc[mt][nt ^ 2][r];
            const float v = (nt < 2) ? a * cs[par] - ap * sn[par]
                                     : a * cs[par] + ap * sn[par];
            lw[(mtl * 16 + g * 4 + r) * 66 + nt * 16 + li] =
                (bf16)(v * outsc);
          }
        }
      }
      __syncthreads();
      // coalesced store: lane L -> row L>>1, d-half (L&1)*32
      const int rowl = lane >> 1, dh = (lane & 1) * 32;
      const int s = (m0 + r0w + pass * 32 + rowl) & (SEQ - 1);
      bf16* gdst = &dst[(bh * SEQ + s) * HD + dh];
      const bf16* lsrc = &lw[rowl * 66 + dh];
#pragma unroll
      for (int c = 0; c < 4; c++)
        *(bf16x8*)&gdst[c * 8] = *(const bf16x8*)&lsrc[c * 8];
    }
  } else {
    // V: transpose-scatter, pack 4 consecutive s per store
#pragma unroll
    for (int mt = 0; mt < 4; mt++)
#pragma unroll
      for (int nt = 0; nt < 4; nt++) {
        const int s = (m0 + r0w + mt * 16 + g * 4) & (SEQ - 1);
        const int d = nt * 16 + li;
        bf16x4 v;
#pragma unroll
        for (int r = 0; r < 4; r++) v[r] = (bf16)acc[mt][nt][r];
        *(bf16x4*)&Vt[(bh * HD + d) * SEQ + s] = v;
      }
  }
}

// ---------------------------------------------------------------------------
// Flash attention v15 (unchanged): full <=8-iter chunking, packed
// deterministic partials, 5 blocks/CU, hoisted LDS offsets, clean/masked
// loop split, native exp2.  entry byte = qt*4 + chunk.
// ---------------------------------------------------------------------------
__device__ const unsigned char CHUNK_TAB[80] = {
    124, 125, 126, 127,
    120, 121, 122, 116, 117, 118, 112, 113, 114, 108, 109, 110,
    104, 105, 106, 100, 101, 102, 96,  97,  98,  92,  93,  94,
    88,  89,  84,  85,  80,  81,  76,  77,  72,  73,  68,  69,
    64,  65,  60,  61,
    56,  52,  48,  44,  40,  36,  32,  28,
    24,  57,  90,  123, 20,  53,  86,  119, 16,  49,  82,  115,
    12,  45,  78,  111, 8,   41,  74,  107, 4,   37,  70,  103,
    0,   33,  66,  99};

__global__ __launch_bounds__(256, 5) void flash_attn15(
    const bf16* __restrict__ Q, const bf16* __restrict__ Kb,
    const bf16* __restrict__ Vt, bf16* __restrict__ Oout,
    float* __restrict__ Opart, float* __restrict__ Lpart) {
  const int bx = blockIdx.x;         // 0..2559
  const unsigned char e = CHUNK_TAB[bx >> 5];
  const int qt = e >> 2, kch = e & 3;
  const int bh = bx & 31;
  const int q0 = qt * 64;
  const int jlo = kch * 8;
  const int jhi = min(jlo + 8, qt + 1);
  const int t = threadIdx.x, w = t >> 6, lane = t & 63, g = lane >> 4,
            li = lane & 15;

  __shared__ bf16 Ks[2][4096];
  __shared__ bf16 Vs[2][4096];

  const bf16* Qh = Q  + (size_t)bh * SEQ * HD;
  const bf16* Kh = Kb + (size_t)bh * SEQ * HD;
  const bf16* Vh = Vt + (size_t)bh * HD * SEQ;

  const int qw = q0 + w * 16;        // this wave's 16 q-rows (q = qw + li)

  bf16x8 qf[2];
#pragma unroll
  for (int ks = 0; ks < 2; ks++)
    qf[ks] = *(const bf16x8*)&Qh[(size_t)(qw + li) * HD + ks * 32 + g * 8];

  f32x4 o[4] = {};   // O^T[dv = dt*16 + g*4 + r][q = li]
  f32x4 o4  = {};    // ones-row accumulator -> l(q=li)
  bf16x4 ones;
#pragma unroll
  for (int r = 0; r < 4; r++) ones[r] = (bf16)1.f;

  // hoisted LDS byte offsets (static-indexed after unroll -> registers)
  int koffB[2][4];
#pragma unroll
  for (int ks = 0; ks < 2; ks++)
#pragma unroll
    for (int nt = 0; nt < 4; nt++) {
      const int rK = nt * 16 + li;
      const int pK = rK * 8 + ((ks * 4 + g) ^ (li & 7));
      koffB[ks][nt] = pK * 16;
    }
  int voffB[4][4];
#pragma unroll
  for (int nt = 0; nt < 4; nt++)
#pragma unroll
    for (int dt = 0; dt < 4; dt++) {
      const int rV = dt * 16 + li;
      const int cg = nt * 2 + (g >> 1);
      const int pV = rV * 8 + (cg ^ (rV & 7));
      voffB[nt][dt] = pV * 16 + (g & 1) * 8;
    }

  const int p0 = w * 128 + lane, p1 = p0 + 64;
  const int sr0 = p0 >> 3, sc0 = ((p0 & 7) ^ (sr0 & 7)) * 8;
  const int sr1 = p1 >> 3, sc1 = ((p1 & 7) ^ (sr1 & 7)) * 8;
  const int lo0 = w * 1024, lo1 = w * 1024 + 512;

  {
    const int jn = jlo * 64;
    gl_lds16(&Kh[(size_t)(jn + sr0) * HD + sc0], &Ks[jlo & 1][lo0]);
    gl_lds16(&Kh[(size_t)(jn + sr1) * HD + sc1], &Ks[jlo & 1][lo1]);
    gl_lds16(&Vh[(size_t)sr0 * SEQ + jn + sc0], &Vs[jlo & 1][lo0]);
    gl_lds16(&Vh[(size_t)sr1 * SEQ + jn + sc1], &Vs[jlo & 1][lo1]);
  }
  __syncthreads();

  for (int ti = jlo; ti < jhi; ++ti) {
    const int cur = ti & 1, nxt = cur ^ 1;
    const char* ksb = (const char*)&Ks[cur][0];
    const char* vsb = (const char*)&Vs[cur][0];
    if (ti + 1 < jhi) {
      const int jn = ti * 64 + 64;
      gl_lds16(&Kh[(size_t)(jn + sr0) * HD + sc0], &Ks[nxt][lo0]);
      gl_lds16(&Kh[(size_t)(jn + sr1) * HD + sc1], &Ks[nxt][lo1]);
      gl_lds16(&Vh[(size_t)sr0 * SEQ + jn + sc0], &Vs[nxt][lo0]);
      gl_lds16(&Vh[(size_t)sr1 * SEQ + jn + sc1], &Vs[nxt][lo1]);
    }

    if (ti < qt) {
      // clean tile: no masking, all 4 nt fragments
      f32x4 sacc[4] = {};
      __builtin_amdgcn_s_setprio(1);
#pragma unroll
      for (int ks = 0; ks < 2; ks++)
#pragma unroll
        for (int nt = 0; nt < 4; nt++) {
          bf16x8 kf = *(const bf16x8*)(ksb + koffB[ks][nt]);
          sacc[nt] = __builtin_amdgcn_mfma_f32_16x16x32_bf16(kf, qf[ks],
                                                             sacc[nt], 0, 0, 0);
        }
      __builtin_amdgcn_s_setprio(0);

      bf16x4 pf[4];
#pragma unroll
      for (int nt = 0; nt < 4; nt++)
#pragma unroll
        for (int r = 0; r < 4; r++) pf[nt][r] = (bf16)EXP2(sacc[nt][r]);

      __builtin_amdgcn_s_setprio(1);
#pragma unroll
      for (int nt = 0; nt < 4; nt++) {
        o4 = mfma_16x16x16_bf16(ones, pf[nt], o4);
#pragma unroll
        for (int dt = 0; dt < 4; dt++) {
          bf16x4 vfrag = *(const bf16x4*)(vsb + voffB[nt][dt]);
          o[dt] = mfma_16x16x16_bf16(vfrag, pf[nt], o[dt]);
        }
      }
      __builtin_amdgcn_s_setprio(0);
    } else {
      // diagonal tile (ti == qt): fragments nt<w clean, nt==w masked,
      // nt>w entirely below the causal boundary
      f32x4 sacc[4] = {};
      __builtin_amdgcn_s_setprio(1);
#pragma unroll
      for (int ks = 0; ks < 2; ks++)
#pragma unroll
        for (int nt = 0; nt < 4; nt++) {
          if (nt > w) continue;
          bf16x8 kf = *(const bf16x8*)(ksb + koffB[ks][nt]);
          sacc[nt] = __builtin_amdgcn_mfma_f32_16x16x32_bf16(kf, qf[ks],
                                                             sacc[nt], 0, 0, 0);
        }
      __builtin_amdgcn_s_setprio(0);

      bf16x4 pf[4];
#pragma unroll
      for (int nt = 0; nt < 4; nt++) {
        if (nt > w) continue;
#pragma unroll
        for (int r = 0; r < 4; r++) {
          float v = sacc[nt][r];
          if (nt == w) {
            const int kk = nt * 16 + g * 4 + r;
            v = (kk <= w * 16 + li) ? v : -1e30f;
          }
          pf[nt][r] = (bf16)EXP2(v);
        }
      }

      __builtin_amdgcn_s_setprio(1);
#pragma unroll
      for (int nt = 0; nt < 4; nt++) {
        if (nt > w) continue;
        o4 = mfma_16x16x16_bf16(ones, pf[nt], o4);
#pragma unroll
        for (int dt = 0; dt < 4; dt++) {
          bf16x4 vfrag = *(const bf16x4*)(vsb + voffB[nt][dt]);
          o[dt] = mfma_16x16x16_bf16(vfrag, pf[nt], o[dt]);
        }
      }
      __builtin_amdgcn_s_setprio(0);
    }
    __syncthreads();
  }

  if (qt <= 7) {
    // single chunk: direct normalized store (rows s < 512)
    const float inv_l = 1.f / o4[0];
    const int b = bh >> 4, h = bh & 15;
    const int s = qw + li;
#pragma unroll
    for (int dt = 0; dt < 4; dt++) {
      bf16x4 ov;
#pragma unroll
      for (int r = 0; r < 4; r++) ov[r] = (bf16)(o[dt][r] * inv_l);
      *(bf16x4*)&Oout[((size_t)(b * SEQ + s)) * DMODEL + h * 64 + dt * 16 +
                      g * 4] = ov;
    }
  } else {
    // packed deterministic partial slot: 2/3/4 slots per row by qt band
    const int s = qw + li;
    int off;
    if (qt < 16)       off = (s - 512) * 2 + kch;
    else if (qt < 24)  off = 1024 + (s - 1024) * 3 + kch;
    else               off = 2560 + (s - 1536) * 4 + kch;
    const size_t slot = (size_t)bh * 4608 + off;
    if (g == 0) Lpart[slot] = o4[0];
    float* od = &Opart[slot * 64];
#pragma unroll
    for (int dt = 0; dt < 4; dt++)
      *(f32x4*)&od[dt * 16 + g * 4] = o[dt];
  }
}

// ---------------------------------------------------------------------------
// Merge rows s in [512,2048): attn = sum_c(Oc) / sum_c(lc), nc = 2/3/4
// grid 1536 x 256, 8 floats/thread
// ---------------------------------------------------------------------------
__global__ __launch_bounds__(256) void attn_merge2(
    const float* __restrict__ Opart, const float* __restrict__ Lpart,
    bf16* __restrict__ attn) {
  const int gi = blockIdx.x * 256 + threadIdx.x;  // 0..393215
  const int row = gi >> 3;                        // bh*1536 + srel
  const int d0 = (gi & 7) * 8;
  const int bh = row / 1536, srel = row - bh * 1536;
  const int b = bh >> 4, h = bh & 15, s = srel + 512;
  int off0, nc;
  if (srel < 512)       { off0 = srel * 2;                nc = 2; }
  else if (srel < 1024) { off0 = 1024 + (srel - 512) * 3; nc = 3; }
  else                  { off0 = 2560 + (srel - 1024) * 4; nc = 4; }
  const size_t base = (size_t)bh * 4608 + off0;
  float lsum = 0.f;
  float acc[8] = {};
  for (int c = 0; c < nc; c++) {
    lsum += Lpart[base + c];
    const float* p = &Opart[(base + c) * 64 + d0];
    float4 a0 = *(const float4*)p;
    float4 a1 = *(const float4*)(p + 4);
    acc[0] += a0.x; acc[1] += a0.y; acc[2] += a0.z; acc[3] += a0.w;
    acc[4] += a1.x; acc[5] += a1.y; acc[6] += a1.z; acc[7] += a1.w;
  }
  const float inv = 1.f / lsum;
  bf16x8 v;
#pragma unroll
  for (int i = 0; i < 8; i++) v[i] = (bf16)(acc[i] * inv);
  *(bf16x8*)&attn[((size_t)(b * SEQ + s)) * DMODEL + h * 64 + d0] = v;
}

// ---------------------------------------------------------------------------
// Launch
// ---------------------------------------------------------------------------
extern "C" void kernel_launch(void* const* d_in, const int* in_sizes, int n_in,
                              void* d_out, int out_size, void* d_ws,
                              size_t ws_size, hipStream_t stream) {
  const float* x     = (const float*)d_in[0];
  // d_in[1] = causal mask (int32) — causality implemented directly
  const float* w_qkv = (const float*)d_in[2];
  const float* w_out = (const float*)d_in[3];
  float* out = (float*)d_out;

  char* ws = (char*)d_ws;
  bf16* WqkvT = (bf16*)(ws);                        //  6,291,456 B
  bf16* WoutT = (bf16*)(ws + 6291456);              //  2,097,152 B
  bf16* xb    = (bf16*)(ws + 8388608);              //  8,388,608 B
  bf16* Qb    = (bf16*)(ws + 16777216);             //  8,388,608 B
  bf16* Kbuf  = (bf16*)(ws + 25165824);             //  8,388,608 B
  bf16* Vt    = (bf16*)(ws + 33554432);             //  8,388,608 B
  bf16* attn  = (bf16*)(ws + 41943040);             //  8,388,608 B
  float* Opart= (float*)(ws + 50331648);            // 37,748,736 B
  float* Lpart= (float*)(ws + 88080384);            //    589,824 B (end ~88.7MB)

  prep_kernel<<<dim3(6144), 256, 0, stream>>>(x, w_qkv, w_out, xb, WqkvT,
                                              WoutT);
  gemm_qkv_rope<<<dim3(N_QKV / 128, M_ROWS / 128), 256, 0, stream>>>(
      xb, WqkvT, Qb, Kbuf, Vt);
  flash_attn15<<<dim3(2560), 256, 0, stream>>>(Qb, Kbuf, Vt, attn, Opart,
                                               Lpart);
  attn_merge2<<<dim3(1536), 256, 0, stream>>>(Opart, Lpart, attn);
  gemm_out64<<<dim3(DMODEL / 128, M_ROWS / 64), 256, 0, stream>>>(
      attn, WoutT, out, M_ROWS, DMODEL, DMODEL);
}